// Round 9
// baseline (116.680 us; speedup 1.0000x reference)
//
#include <hip/hip_runtime.h>
#include <math.h>

#define B_ 2
#define C_ 128
#define H_ 64
#define W_ 64
#define F_ 16
#define U_ 9
#define MD_ 4
#define HW_ (H_*W_)
#define BF_ (B_*F_)

typedef float f32x4 __attribute__((ext_vector_type(4)));
typedef float f32x2 __attribute__((ext_vector_type(2)));
typedef _Float16 f16x2 __attribute__((ext_vector_type(2)));
typedef _Float16 f16x4 __attribute__((ext_vector_type(4)));
typedef _Float16 f16x8 __attribute__((ext_vector_type(8)));

// Scales (exact powers of two; leaky_relu commutes with positive scaling).
// fp16 hi/lo split -> ~2^-21 rel error per term (verified r2/r4/r5/r6/r7/r8).
#define XSCALE   64.0f
#define WSCALE   256.0f
#define UNSCALE  (1.0f / 16384.0f)

// LDS map (floats), per 512-thr block (16-px tile):
//  [0,5832)      pvol[(fl*81+uv)*18+px]          (epilogue)
//  [5832,6344)   sm ; [6344,6856) si ; [6856,9928) sred[6][512]
//  [9928,9960)   fx,fy (flow f=0 capture for warp tail)
//  [10000,12112) refT[px*132 + c], px 0..15, c 0..127 (staged once, prologue)
// Main loop reads ONLY refT + global tar -> no barriers until the epilogue.
#define SM_  5832
#define SI_  6344
#define SU_  6856
#define FX_  9928
#define FY_  9944
#define REFO 10000
#define LDSZ 12112

static __device__ __forceinline__ f16x8 cat4(f16x2 a, f16x2 b, f16x2 c, f16x2 d) {
    f16x4 ab = __builtin_shufflevector(a, b, 0, 1, 2, 3);
    f16x4 cd = __builtin_shufflevector(c, d, 0, 1, 2, 3);
    return __builtin_shufflevector(ab, cd, 0, 1, 2, 3, 4, 5, 6, 7);
}

// exact hi/lo fp16 split of a packed f32 pair
static __device__ __forceinline__ void split2(f32x2 p, f16x2& hi, f16x2& lo) {
    hi = __builtin_bit_cast(f16x2, __builtin_amdgcn_cvt_pkrtz(p.x, p.y));
    f32x2 hf; hf.x = (float)hi.x; hf.y = (float)hi.y;
    f32x2 l = p - hf;
    lo = __builtin_bit_cast(f16x2, __builtin_amdgcn_cvt_pkrtz(l.x, l.y));
}

// Fused cost-volume + flow_reg + warp v5: barrier-free main loop.
// Block = 512 thr = 8 waves = 8 uv-chunks (11,10x7 ascending), 16-px tile.
// Grid = 512 = (b,y,xq) XCD-chunked; launch_bounds(512,2): empirically the 2nd
// arg is min-blocks/CU on this toolchain -> VGPR cap 128 (r6's (512,4) spilled).
// MFMA 16x16x32_f16: A = W[16f][32c], B = X[32c][16px]; D row f=grp*4+r, col=ml
// (fragment mapping verified by r2..r8 passes).
// Tar is read directly from global (L1-resident tile: 27 KB/kc < 32 KB L1):
// addr = SGPR plane base (kc,c8 uniform) + per-lane voffset precomputed per uv.
// Zero padding: row-OOB -> whole uv skipped (X=0 contributes nothing);
// col-OOB -> mask-multiply the product (leaky(0)=0).
__global__ __launch_bounds__(512, 2)
void fused_kernel(const float* __restrict__ ref,
                  const float* __restrict__ tar,
                  const float* __restrict__ pw,
                  float* __restrict__ out0,
                  float* __restrict__ warped) {
    const int t    = threadIdx.x;
    const int lane = t & 63;
    const int wid  = t >> 6;            // wave = uv-chunk
    const int ml   = lane & 15;         // B col = pixel ; A row = f
    const int grp  = lane >> 4;         // k-group (c = grp*8+j) ; D: f = grp*4+r

    // XCD-chunked bijective decode: grid 512 = 8 XCD x 64 contiguous (b,y,xq)
    const int n0 = blockIdx.x;
    const int L  = (n0 & 7) * 64 + (n0 >> 3);
    const int b  = L >> 8;
    const int y  = (L >> 2) & 63;
    const int x0 = (L & 3) * 16;

    const int start = wid ? (1 + wid * 10) : 0;   // chunk [start,start+n), n=wid?10:11

    __shared__ float lds[LDSZ];

    const float* refB = ref + ((size_t)b * C_) * HW_ + y * W_ + x0;
    const float* tarB = tar + ((size_t)b * C_) * HW_;

    // uv decode + per-uv address/mask precompute (i=10 only used by wave 0)
    int uA[11], vA[11], voff[11];
    float mf[11];
    bool rok[11];
    #pragma unroll
    for (int i = 0; i < 11; ++i) {
        int uv = start + i;
        int uu = uv / 9;
        uA[i] = uu; vA[i] = uv - uu * 9;
        int ysr = y + vA[i] - 4;
        rok[i] = ((unsigned)ysr < 64u);
        int xc  = x0 + ml + uA[i] - 4;
        mf[i]   = ((unsigned)xc < 64u) ? 1.f : 0.f;
        int xcl = xc  < 0 ? 0 : (xc  > 63 ? 63 : xc);
        int ycl = ysr < 0 ? 0 : (ysr > 63 ? 63 : ysr);
        voff[i] = grp * 8 * HW_ + ycl * W_ + xcl;   // lane-varying, kc-invariant
    }

    // ---- stage refT once (2048 elems), scaled x64; the only pre-epilogue barrier
    #pragma unroll
    for (int it = 0; it < 4; ++it) {
        int idx = it * 512 + t;
        int c = idx >> 4, px = idx & 15;
        lds[REFO + px * 132 + c] = refB[(size_t)c * HW_ + px] * XSCALE;
    }
    __syncthreads();

    f32x4 acc[11];
    #pragma unroll
    for (int i = 0; i < 11; ++i) acc[i] = f32x4{0.f, 0.f, 0.f, 0.f};

    #pragma unroll
    for (int kc = 0; kc < 4; ++kc) {
        f32x4 wa = *(const f32x4*)(pw + ml * C_ + kc * 32 + grp * 8);
        f32x4 wb = *(const f32x4*)(pw + ml * C_ + kc * 32 + grp * 8 + 4);
        f16x2 wh[4], wl[4];
        {
            f32x2 p;
            p.x = wa.x * WSCALE; p.y = wa.y * WSCALE; split2(p, wh[0], wl[0]);
            p.x = wa.z * WSCALE; p.y = wa.w * WSCALE; split2(p, wh[1], wl[1]);
            p.x = wb.x * WSCALE; p.y = wb.y * WSCALE; split2(p, wh[2], wl[2]);
            p.x = wb.z * WSCALE; p.y = wb.w * WSCALE; split2(p, wh[3], wl[3]);
        }
        f16x8 whi = cat4(wh[0], wh[1], wh[2], wh[3]);
        f16x8 wlo = cat4(wl[0], wl[1], wl[2], wl[3]);

        // ref fragment: 2 x ds_read_b128, stride 132
        f32x4 rva = *(const f32x4*)(lds + REFO + ml * 132 + kc * 32 + grp * 8);
        f32x4 rvb = *(const f32x4*)(lds + REFO + ml * 132 + kc * 32 + grp * 8 + 4);
        f32x2 rv2[4];
        rv2[0].x = rva.x; rv2[0].y = rva.y;
        rv2[1].x = rva.z; rv2[1].y = rva.w;
        rv2[2].x = rvb.x; rv2[2].y = rvb.y;
        rv2[3].x = rvb.z; rv2[3].y = rvb.w;

        const float* pk = tarB + (size_t)(kc * 32) * HW_;   // uniform kc base

        // 8 global_load_dword per uv: SGPR plane base (c8 uniform) + voff[i]
#define UVBODY(i) if (rok[i]) {                                               \
        float tv[8];                                                          \
        _Pragma("unroll")                                                     \
        for (int c8 = 0; c8 < 8; ++c8)                                        \
            tv[c8] = pk[(size_t)c8 * HW_ + voff[i]];                          \
        f32x2 mp; mp.x = mf[i]; mp.y = mf[i];                                 \
        f16x2 xh4[4], xl4[4];                                                 \
        _Pragma("unroll")                                                     \
        for (int jp = 0; jp < 4; ++jp) {                                      \
            f32x2 tj; tj.x = tv[2 * jp]; tj.y = tv[2 * jp + 1];               \
            f32x2 p  = rv2[jp] * tj;                                          \
            p = p * mp;                                                       \
            f32x2 p1 = p * 0.1f;                                              \
            p = __builtin_elementwise_max(p, p1);                             \
            split2(p, xh4[jp], xl4[jp]);                                      \
        }                                                                     \
        f16x8 xhi = cat4(xh4[0], xh4[1], xh4[2], xh4[3]);                     \
        f16x8 xlo = cat4(xl4[0], xl4[1], xl4[2], xl4[3]);                     \
        acc[i] = __builtin_amdgcn_mfma_f32_16x16x32_f16(whi, xhi, acc[i], 0, 0, 0); \
        acc[i] = __builtin_amdgcn_mfma_f32_16x16x32_f16(wlo, xhi, acc[i], 0, 0, 0); \
        acc[i] = __builtin_amdgcn_mfma_f32_16x16x32_f16(whi, xlo, acc[i], 0, 0, 0); }

        #pragma unroll
        for (int i = 0; i < 10; ++i) UVBODY(i);
        if (wid == 0) UVBODY(10);
    }

    // ---- epilogue: 4 passes of 4 f-planes; flow_reg per (f, px) ----
    const int rem = t & 63;
    const int fl  = rem >> 4;
    const int px  = rem & 15;

    for (int P = 0; P < 4; ++P) {
        // bounce this wave's uv-chunk for f = 4P..4P+3 (lanes grp==P hold them)
#define BOUNCE(i) {                                                           \
        if (grp == P) {                                                       \
            int ba = (start + (i)) * 18 + ml;                                 \
            lds[ba        ] = acc[i][0] * UNSCALE;                            \
            lds[ba + 1458 ] = acc[i][1] * UNSCALE;                            \
            lds[ba + 2916 ] = acc[i][2] * UNSCALE;                            \
            lds[ba + 4374 ] = acc[i][3] * UNSCALE; } }
        #pragma unroll
        for (int i = 0; i < 10; ++i) BOUNCE(i);
        if (wid == 0) BOUNCE(10);
        __syncthreads();

        // PH1: per-thread local argmax over its chunk (ascending, strict >)
        float vv[11];
        #pragma unroll
        for (int i = 0; i < 10; ++i)
            vv[i] = lds[fl * 1458 + (start + i) * 18 + px];
        if (wid == 0) vv[10] = lds[fl * 1458 + 10 * 18 + px];
        float mv = vv[0]; int bi = start;
        #pragma unroll
        for (int i = 1; i < 10; ++i)
            if (vv[i] > mv) { mv = vv[i]; bi = start + i; }
        if (wid == 0 && vv[10] > mv) { mv = vv[10]; bi = 10; }
        lds[SM_ + t] = mv; lds[SI_ + t] = (float)bi;
        __syncthreads();

        // ascending 8-chunk combine -> global first-occurrence argmax
        float m = lds[SM_ + rem]; int best = (int)lds[SI_ + rem];
        #pragma unroll
        for (int k = 1; k < 8; ++k) {
            float mk = lds[SM_ + k * 64 + rem];
            if (mk > m) { m = mk; best = (int)lds[SI_ + k * 64 + rem]; }
        }
        int ub = best / 9, vb = best - 9 * (best / 9);

        // PH2: masked/global softmax partials over the chunk
        float S = 0.f, A = 0.f, Sx = 0.f, Sy = 0.f, gS = 0.f, gA = 0.f;
#define PH2B(i) {                                                             \
        float d = vv[i] - m; float z = __expf(d);                             \
        gS += z; gA = fmaf(z, d, gA);                                         \
        int duc = uA[i] - ub, dvc = vA[i] - vb;                               \
        bool msk = (duc <= 3) && (duc >= -3) && (dvc <= 3) && (dvc >= -3);    \
        float zm = msk ? z : 0.f, dm = msk ? d : 0.f;                         \
        S += zm; A = fmaf(zm, dm, A);                                         \
        Sx = fmaf(zm, (float)(uA[i] - MD_), Sx);                              \
        Sy = fmaf(zm, (float)(vA[i] - MD_), Sy); }
        #pragma unroll
        for (int i = 0; i < 10; ++i) PH2B(i);
        if (wid == 0) PH2B(10);

        lds[SU_ + 0 * 512 + t] = S;  lds[SU_ + 1 * 512 + t] = A;
        lds[SU_ + 2 * 512 + t] = Sx; lds[SU_ + 3 * 512 + t] = Sy;
        lds[SU_ + 4 * 512 + t] = gS; lds[SU_ + 5 * 512 + t] = gA;
        __syncthreads();

        if (t < 64) {
            float rq[6];
            #pragma unroll
            for (int q = 0; q < 6; ++q) {
                float s = lds[SU_ + q * 512 + t];
                #pragma unroll
                for (int k = 1; k < 8; ++k) s += lds[SU_ + q * 512 + k * 64 + t];
                rq[q] = s;
            }
            float invS = 1.f / rq[0];
            float outx = rq[2] * invS;
            float outy = rq[3] * invS;
            float lent = (logf(rq[0]) - rq[1] * invS) * (1.0f / logf(49.0f));
            float gent = (logf(rq[4]) - rq[5] / rq[4]) * (1.0f / logf(81.0f));
            float* op = out0 + ((size_t)(b * F_ + P * 4 + (t >> 4)) * 4) * HW_
                      + y * W_ + x0 + (t & 15);
            op[0 * HW_] = outx;
            op[1 * HW_] = outy;
            op[2 * HW_] = lent;
            op[3 * HW_] = gent;
            if (P == 0 && t < 16) { lds[FX_ + t] = outx; lds[FY_ + t] = outy; }
        }
        // no end-of-pass barrier needed (verified r8): pass P+1's writes are
        // ordered after its own barriers, past every pass-P reader.
    }

    // ---- fused warp tail: this block's 16 px, all 128 c (flow = f0, pass 0;
    //      FX_/FY_ written >=2 barriers ago -> visible) ----
    {
        const int pxi = t & 15;
        const int xw  = x0 + pxi;
        float fx = lds[FX_ + pxi], fy = lds[FY_ + pxi];
        float pxw = (float)xw + fx;
        float pyw = (float)y  + fy;
        bool inb = (fabsf(2.0f * pxw / 63.0f - 1.0f) < 1.0f) &&
                   (fabsf(2.0f * pyw / 63.0f - 1.0f) < 1.0f);
        float xf = floorf(pxw), yf = floorf(pyw);
        float wx = pxw - xf, wy = pyw - yf;
        int x0i = (int)xf, y0i = (int)yf;
        auto off = [&](int yi, int xi, float wgt, float& mw) -> int {
            bool v = ((unsigned)xi < (unsigned)W_) && ((unsigned)yi < (unsigned)H_);
            int xc = xi < 0 ? 0 : (xi > W_ - 1 ? W_ - 1 : xi);
            int yc = yi < 0 ? 0 : (yi > H_ - 1 ? H_ - 1 : yi);
            mw = v ? wgt : 0.f;
            return yc * W_ + xc;
        };
        float m00, m01, m10, m11;
        int o00 = off(y0i,     x0i,     (1.f - wx) * (1.f - wy), m00);
        int o01 = off(y0i,     x0i + 1, wx * (1.f - wy),         m01);
        int o10 = off(y0i + 1, x0i,     (1.f - wx) * wy,         m10);
        int o11 = off(y0i + 1, x0i + 1, wx * wy,                 m11);
        #pragma unroll
        for (int it = 0; it < 4; ++it) {
            int c = (t >> 4) + 32 * it;
            const float* img = tarB + (size_t)c * HW_;
            float a = img[o00] * m00 + img[o01] * m01
                    + img[o10] * m10 + img[o11] * m11;
            warped[((size_t)(b * C_ + c)) * HW_ + y * W_ + xw] = inb ? a : 0.f;
        }
    }
}

extern "C" void kernel_launch(void* const* d_in, const int* in_sizes, int n_in,
                              void* d_out, int out_size, void* d_ws, size_t ws_size,
                              hipStream_t stream) {
    const float* ref = (const float*)d_in[0];
    const float* tar = (const float*)d_in[1];
    const float* pw  = (const float*)d_in[2];
    float* out0 = (float*)d_out;                       // (B*F, 4, H, W)
    float* out1 = out0 + (size_t)BF_ * 4 * HW_;        // (B, C, H, W)
    (void)d_ws; (void)ws_size;                         // workspace unused

    fused_kernel<<<512, 512, 0, stream>>>(ref, tar, pw, out0, out1);
}

// Round 10
// 108.209 us; speedup vs baseline: 1.0783x; 1.0783x over previous
//
#include <hip/hip_runtime.h>
#include <math.h>

#define B_ 2
#define C_ 128
#define H_ 64
#define W_ 64
#define F_ 16
#define U_ 9
#define MD_ 4
#define HW_ (H_*W_)
#define BF_ (B_*F_)

typedef float f32x4 __attribute__((ext_vector_type(4)));
typedef float f32x2 __attribute__((ext_vector_type(2)));
typedef _Float16 f16x2 __attribute__((ext_vector_type(2)));
typedef _Float16 f16x4 __attribute__((ext_vector_type(4)));
typedef _Float16 f16x8 __attribute__((ext_vector_type(8)));

// Scales (exact powers of two; leaky_relu commutes with positive scaling).
// fp16 hi/lo split -> ~2^-21 rel error per term (verified r2/r4..r9).
#define XSCALE   64.0f
#define WSCALE   256.0f
#define UNSCALE  (1.0f / 16384.0f)

// LDS map (floats), per 512-thr block (16-px tile):
//  [0,7344)       tar buf0 [seg*34 + c], seg = r*24+col (r 0..8, col 0..23), c 0..31
//  [7344,14688)   tar buf1 (double buffer, 1 barrier/kc)
//  [14688,16800)  refT[px*132 + c], px 0..15, c 0..127 (staged once)
//  epilogue reuse (all inside dead tar bufs after the final kc barrier):
//  [0,5832) pvol ; [5832,6344) sm ; [6344,6856) si ; [6856,9928) sred[6][512]
//  [9928,9960) fx,fy
#define TB0  0
#define TB1  7344
#define TSTR 34
#define REFO 14688
#define SM_  5832
#define SI_  6344
#define SU_  6856
#define FX_  9928
#define FY_  9944
#define LDSZ 16800

static __device__ __forceinline__ f16x8 cat4(f16x2 a, f16x2 b, f16x2 c, f16x2 d) {
    f16x4 ab = __builtin_shufflevector(a, b, 0, 1, 2, 3);
    f16x4 cd = __builtin_shufflevector(c, d, 0, 1, 2, 3);
    return __builtin_shufflevector(ab, cd, 0, 1, 2, 3, 4, 5, 6, 7);
}

// exact hi/lo fp16 split of a packed f32 pair
static __device__ __forceinline__ void split2(f32x2 p, f16x2& hi, f16x2& lo) {
    hi = __builtin_bit_cast(f16x2, __builtin_amdgcn_cvt_pkrtz(p.x, p.y));
    f32x2 hf; hf.x = (float)hi.x; hf.y = (float)hi.y;
    f32x2 l = p - hf;
    lo = __builtin_bit_cast(f16x2, __builtin_amdgcn_cvt_pkrtz(l.x, l.y));
}

// Fused cost-volume + flow_reg + warp v6: LDS dbuf + explicit uv software
// pipeline + conflict-free coalesced staging.
// Block = 512 thr = 8 waves = 8 uv-chunks (11,10x7 ascending), 16-px tile.
// Grid = 512 = (b,y,xq) XCD-chunked; (512,2) -> VGPR cap 128 (empirical:
// 2nd arg is min-blocks/CU; (512,4) spilled catastrophically in r6).
// MFMA 16x16x32_f16: A = W[16f][32c], B = X[32c][16px]; D row f=grp*4+r, col=ml
// (fragment mapping verified by r2..r9 passes).
__global__ __launch_bounds__(512, 2)
void fused_kernel(const float* __restrict__ ref,
                  const float* __restrict__ tar,
                  const float* __restrict__ pw,
                  float* __restrict__ out0,
                  float* __restrict__ warped) {
    const int t    = threadIdx.x;
    const int lane = t & 63;
    const int wid  = t >> 6;            // wave = uv-chunk
    const int ml   = lane & 15;         // B col = pixel ; A row = f
    const int grp  = lane >> 4;         // k-group (c = grp*8+j) ; D: f = grp*4+r

    // XCD-chunked bijective decode: grid 512 = 8 XCD x 64 contiguous (b,y,xq)
    const int n0 = blockIdx.x;
    const int L  = (n0 & 7) * 64 + (n0 >> 3);
    const int b  = L >> 8;
    const int y  = (L >> 2) & 63;
    const int xq = L & 3;
    const int x0 = xq * 16;

    const int start = wid ? (1 + wid * 10) : 0;   // chunk [start,start+n), n=wid?10:11

    __shared__ float lds[LDSZ];

    const float* refB = ref + ((size_t)b * C_) * HW_ + y * W_ + x0;
    const float* tarB = tar + ((size_t)b * C_) * HW_;

    // per-uv LDS seg offsets (lane-uniform; i=10 only used by wave 0 — for
    // other waves uv=81 gives a valid harmless LDS offset, result unused)
    int off[11];
    #pragma unroll
    for (int i = 0; i < 11; ++i) {
        int uv = start + i;
        int uu = uv / 9;
        off[i] = ((uv - uu * 9) * 24 + uu) * TSTR;
    }
    const int mlg = ml * TSTR + grp * 8;

    // ---- staging role: t<288 -> (c = t&31, r = t>>5), 24-col window ----
    // ds_write bank = (16r + 2j + c) % 32: c spans all banks -> conflict-free.
    const int sc = t & 31;
    const int sr = t >> 5;
    const bool sact = (t < 288);
    const int ysr  = y + sr - 4;
    const bool sok = sact && ((unsigned)ysr < 64u);
    // fault-safe aligned load window [xlo, xlo+24); block-uniform shift sh
    const int xlo = (xq == 0) ? 0 : (xq == 3 ? 40 : x0 - 4);
    const int sh  = x0 - 4 - xlo;                 // -4, 0, +4
    const float* tS = tarB + (size_t)sc * HW_ + (sok ? ysr : 0) * W_ + xlo;
    unsigned cmask = 0;                           // tile col j valid (x in [0,64))
    #pragma unroll
    for (int j = 0; j < 24; ++j)
        if ((unsigned)(x0 - 4 + j) < 64u) cmask |= (1u << j);

    f32x4 g[6];
#define ISSUE(KC) if (sok) {                                                  \
        const float* gp = tS + (size_t)((KC) * 32) * HW_;                     \
        _Pragma("unroll")                                                     \
        for (int q = 0; q < 6; ++q) g[q] = *(const f32x4*)(gp + 4 * q);       \
    }

    // write tile col j <- g[(j+S)/4][(j+S)%4]; OOB j+S folds to 0 at compile
#define SWR(BUF, S) {                                                         \
        float* dst = lds + (BUF) + (sr * 24) * TSTR + sc;                     \
        _Pragma("unroll")                                                     \
        for (int j = 0; j < 24; ++j) {                                        \
            float v_ = 0.f;                                                   \
            if ((j + (S)) >= 0 && (j + (S)) < 24)                             \
                if ((cmask >> j) & 1u) v_ = g[(j + (S)) >> 2][(j + (S)) & 3]; \
            dst[j * TSTR] = v_;                                               \
        } }

#define SWRITE(KC, BUF) {                                                     \
        if (sok) {                                                            \
            if (sh == 0)     { SWR(BUF, 0) }                                  \
            else if (sh < 0) { SWR(BUF, -4) }                                 \
            else             { SWR(BUF, 4) }                                  \
        } else if (sact && (KC) < 2) {  /* row-OOB: zero once per buffer */   \
            float* dst = lds + (BUF) + (sr * 24) * TSTR + sc;                 \
            _Pragma("unroll")                                                 \
            for (int j = 0; j < 24; ++j) dst[j * TSTR] = 0.f;                 \
        } }

#define TCOMP(SL, I) {                                                        \
        f16x2 xh4[4], xl4[4];                                                 \
        _Pragma("unroll")                                                     \
        for (int jp = 0; jp < 4; ++jp) {                                      \
            f32x2 p  = rv2[jp] * tv[SL][jp];                                  \
            f32x2 p1 = p * 0.1f;                                              \
            p = __builtin_elementwise_max(p, p1);                             \
            split2(p, xh4[jp], xl4[jp]);                                      \
        }                                                                     \
        f16x8 xhi = cat4(xh4[0], xh4[1], xh4[2], xh4[3]);                     \
        f16x8 xlo = cat4(xl4[0], xl4[1], xl4[2], xl4[3]);                     \
        acc[I] = __builtin_amdgcn_mfma_f32_16x16x32_f16(whi, xhi, acc[I], 0, 0, 0); \
        acc[I] = __builtin_amdgcn_mfma_f32_16x16x32_f16(wlo, xhi, acc[I], 0, 0, 0); \
        acc[I] = __builtin_amdgcn_mfma_f32_16x16x32_f16(whi, xlo, acc[I], 0, 0, 0); }

    f32x4 acc[11];
    #pragma unroll
    for (int i = 0; i < 11; ++i) acc[i] = f32x4{0.f, 0.f, 0.f, 0.f};

    // ---- prologue: stage ref + kc0, issue kc1 ----
    ISSUE(0);
    #pragma unroll
    for (int it = 0; it < 4; ++it) {
        int idx = it * 512 + t;
        int c = idx >> 4, px = idx & 15;
        lds[REFO + px * 132 + c] = refB[(size_t)c * HW_ + px] * XSCALE;
    }
    SWRITE(0, TB0);
    ISSUE(1);
    __syncthreads();

    #pragma unroll
    for (int kc = 0; kc < 4; ++kc) {
        const int tb = (kc & 1) ? TB1 : TB0;

        f32x4 wa = *(const f32x4*)(pw + ml * C_ + kc * 32 + grp * 8);
        f32x4 wb = *(const f32x4*)(pw + ml * C_ + kc * 32 + grp * 8 + 4);
        f16x2 wh[4], wl[4];
        {
            f32x2 p;
            p.x = wa.x * WSCALE; p.y = wa.y * WSCALE; split2(p, wh[0], wl[0]);
            p.x = wa.z * WSCALE; p.y = wa.w * WSCALE; split2(p, wh[1], wl[1]);
            p.x = wb.x * WSCALE; p.y = wb.y * WSCALE; split2(p, wh[2], wl[2]);
            p.x = wb.z * WSCALE; p.y = wb.w * WSCALE; split2(p, wh[3], wl[3]);
        }
        f16x8 whi = cat4(wh[0], wh[1], wh[2], wh[3]);
        f16x8 wlo = cat4(wl[0], wl[1], wl[2], wl[3]);

        // ref fragment: 2 x ds_read_b128, stride 132
        f32x4 rva = *(const f32x4*)(lds + REFO + ml * 132 + kc * 32 + grp * 8);
        f32x4 rvb = *(const f32x4*)(lds + REFO + ml * 132 + kc * 32 + grp * 8 + 4);
        f32x2 rv2[4];
        rv2[0].x = rva.x; rv2[0].y = rva.y;
        rv2[1].x = rva.z; rv2[1].y = rva.w;
        rv2[2].x = rvb.x; rv2[2].y = rvb.y;
        rv2[3].x = rvb.z; rv2[3].y = rvb.w;

        // ---- 1-deep uv software pipeline: load uv i+1 while computing uv i
        f32x2 tv[2][4];
        {
            const float* tp = lds + tb + off[0] + mlg;
            tv[0][0] = *(const f32x2*)(tp);     tv[0][1] = *(const f32x2*)(tp + 2);
            tv[0][2] = *(const f32x2*)(tp + 4); tv[0][3] = *(const f32x2*)(tp + 6);
        }
        #pragma unroll
        for (int i = 0; i < 10; ++i) {
            const int nx = (i + 1) & 1, cu = i & 1;
            const float* tp = lds + tb + off[i + 1] + mlg;
            tv[nx][0] = *(const f32x2*)(tp);     tv[nx][1] = *(const f32x2*)(tp + 2);
            tv[nx][2] = *(const f32x2*)(tp + 4); tv[nx][3] = *(const f32x2*)(tp + 6);
            TCOMP(cu, i);
        }
        if (wid == 0) TCOMP(0, 10);

        // stage next tile into the other buffer (its readers finished at the
        // barrier entering this kc), then refill prefetch regs
        if (kc == 0) { SWRITE(1, TB1); ISSUE(2); }
        else if (kc == 1) { SWRITE(2, TB0); ISSUE(3); }
        else if (kc == 2) { SWRITE(3, TB1); }
        __syncthreads();
    }

    // ---- epilogue: 4 passes of 4 f-planes; flow_reg per (f, px) ----
    int uA[11], vA[11];
    #pragma unroll
    for (int i = 0; i < 11; ++i) {
        int uv = start + i;
        int uu = uv / 9;
        uA[i] = uu; vA[i] = uv - uu * 9;
    }
    const int rem = t & 63;
    const int fl  = rem >> 4;
    const int px  = rem & 15;

    for (int P = 0; P < 4; ++P) {
#define BOUNCE(i) {                                                           \
        if (grp == P) {                                                       \
            int ba = (start + (i)) * 18 + ml;                                 \
            lds[ba        ] = acc[i][0] * UNSCALE;                            \
            lds[ba + 1458 ] = acc[i][1] * UNSCALE;                            \
            lds[ba + 2916 ] = acc[i][2] * UNSCALE;                            \
            lds[ba + 4374 ] = acc[i][3] * UNSCALE; } }
        #pragma unroll
        for (int i = 0; i < 10; ++i) BOUNCE(i);
        if (wid == 0) BOUNCE(10);
        __syncthreads();

        // PH1: per-thread local argmax over its chunk (ascending, strict >)
        float vv[11];
        #pragma unroll
        for (int i = 0; i < 10; ++i)
            vv[i] = lds[fl * 1458 + (start + i) * 18 + px];
        if (wid == 0) vv[10] = lds[fl * 1458 + 10 * 18 + px];
        float mv = vv[0]; int bi = start;
        #pragma unroll
        for (int i = 1; i < 10; ++i)
            if (vv[i] > mv) { mv = vv[i]; bi = start + i; }
        if (wid == 0 && vv[10] > mv) { mv = vv[10]; bi = 10; }
        lds[SM_ + t] = mv; lds[SI_ + t] = (float)bi;
        __syncthreads();

        // ascending 8-chunk combine -> global first-occurrence argmax
        float m = lds[SM_ + rem]; int best = (int)lds[SI_ + rem];
        #pragma unroll
        for (int k = 1; k < 8; ++k) {
            float mk = lds[SM_ + k * 64 + rem];
            if (mk > m) { m = mk; best = (int)lds[SI_ + k * 64 + rem]; }
        }
        int ub = best / 9, vb = best - 9 * (best / 9);

        // PH2: masked/global softmax partials over the chunk
        float S = 0.f, A = 0.f, Sx = 0.f, Sy = 0.f, gS = 0.f, gA = 0.f;
#define PH2B(i) {                                                             \
        float d = vv[i] - m; float z = __expf(d);                             \
        gS += z; gA = fmaf(z, d, gA);                                         \
        int duc = uA[i] - ub, dvc = vA[i] - vb;                               \
        bool msk = (duc <= 3) && (duc >= -3) && (dvc <= 3) && (dvc >= -3);    \
        float zm = msk ? z : 0.f, dm = msk ? d : 0.f;                         \
        S += zm; A = fmaf(zm, dm, A);                                         \
        Sx = fmaf(zm, (float)(uA[i] - MD_), Sx);                              \
        Sy = fmaf(zm, (float)(vA[i] - MD_), Sy); }
        #pragma unroll
        for (int i = 0; i < 10; ++i) PH2B(i);
        if (wid == 0) PH2B(10);

        lds[SU_ + 0 * 512 + t] = S;  lds[SU_ + 1 * 512 + t] = A;
        lds[SU_ + 2 * 512 + t] = Sx; lds[SU_ + 3 * 512 + t] = Sy;
        lds[SU_ + 4 * 512 + t] = gS; lds[SU_ + 5 * 512 + t] = gA;
        __syncthreads();

        if (t < 64) {
            float rq[6];
            #pragma unroll
            for (int q = 0; q < 6; ++q) {
                float s = lds[SU_ + q * 512 + t];
                #pragma unroll
                for (int k = 1; k < 8; ++k) s += lds[SU_ + q * 512 + k * 64 + t];
                rq[q] = s;
            }
            float invS = 1.f / rq[0];
            float outx = rq[2] * invS;
            float outy = rq[3] * invS;
            float lent = (logf(rq[0]) - rq[1] * invS) * (1.0f / logf(49.0f));
            float gent = (logf(rq[4]) - rq[5] / rq[4]) * (1.0f / logf(81.0f));
            float* op = out0 + ((size_t)(b * F_ + P * 4 + (t >> 4)) * 4) * HW_
                      + y * W_ + x0 + (t & 15);
            op[0 * HW_] = outx;
            op[1 * HW_] = outy;
            op[2 * HW_] = lent;
            op[3 * HW_] = gent;
            if (P == 0 && t < 16) { lds[FX_ + t] = outx; lds[FY_ + t] = outy; }
        }
        // no end-of-pass barrier needed (verified r7/r8): pass P+1's writes
        // are ordered after its own barriers, past every pass-P reader.
    }

    // ---- fused warp tail: this block's 16 px, all 128 c (flow = f0, pass 0;
    //      FX_/FY_ written >=2 barriers ago -> visible) ----
    {
        const int pxi = t & 15;
        const int xw  = x0 + pxi;
        float fx = lds[FX_ + pxi], fy = lds[FY_ + pxi];
        float pxw = (float)xw + fx;
        float pyw = (float)y  + fy;
        bool inb = (fabsf(2.0f * pxw / 63.0f - 1.0f) < 1.0f) &&
                   (fabsf(2.0f * pyw / 63.0f - 1.0f) < 1.0f);
        float xf = floorf(pxw), yf = floorf(pyw);
        float wx = pxw - xf, wy = pyw - yf;
        int x0i = (int)xf, y0i = (int)yf;
        auto offn = [&](int yi, int xi, float wgt, float& mw) -> int {
            bool v = ((unsigned)xi < (unsigned)W_) && ((unsigned)yi < (unsigned)H_);
            int xc = xi < 0 ? 0 : (xi > W_ - 1 ? W_ - 1 : xi);
            int yc = yi < 0 ? 0 : (yi > H_ - 1 ? H_ - 1 : yi);
            mw = v ? wgt : 0.f;
            return yc * W_ + xc;
        };
        float m00, m01, m10, m11;
        int o00 = offn(y0i,     x0i,     (1.f - wx) * (1.f - wy), m00);
        int o01 = offn(y0i,     x0i + 1, wx * (1.f - wy),         m01);
        int o10 = offn(y0i + 1, x0i,     (1.f - wx) * wy,         m10);
        int o11 = offn(y0i + 1, x0i + 1, wx * wy,                 m11);
        #pragma unroll
        for (int it = 0; it < 4; ++it) {
            int c = (t >> 4) + 32 * it;
            const float* img = tarB + (size_t)c * HW_;
            float a = img[o00] * m00 + img[o01] * m01
                    + img[o10] * m10 + img[o11] * m11;
            warped[((size_t)(b * C_ + c)) * HW_ + y * W_ + xw] = inb ? a : 0.f;
        }
    }
}

extern "C" void kernel_launch(void* const* d_in, const int* in_sizes, int n_in,
                              void* d_out, int out_size, void* d_ws, size_t ws_size,
                              hipStream_t stream) {
    const float* ref = (const float*)d_in[0];
    const float* tar = (const float*)d_in[1];
    const float* pw  = (const float*)d_in[2];
    float* out0 = (float*)d_out;                       // (B*F, 4, H, W)
    float* out1 = out0 + (size_t)BF_ * 4 * HW_;        // (B, C, H, W)
    (void)d_ws; (void)ws_size;                         // workspace unused

    fused_kernel<<<512, 512, 0, stream>>>(ref, tar, pw, out0, out1);
}

// Round 11
// 102.235 us; speedup vs baseline: 1.1413x; 1.0584x over previous
//
#include <hip/hip_runtime.h>
#include <math.h>

#define B_ 2
#define C_ 128
#define H_ 64
#define W_ 64
#define F_ 16
#define U_ 9
#define MD_ 4
#define HW_ (H_*W_)
#define BF_ (B_*F_)

typedef float f32x4 __attribute__((ext_vector_type(4)));
typedef float f32x2 __attribute__((ext_vector_type(2)));
typedef _Float16 f16x2 __attribute__((ext_vector_type(2)));
typedef _Float16 f16x4 __attribute__((ext_vector_type(4)));
typedef _Float16 f16x8 __attribute__((ext_vector_type(8)));

// Scales (exact powers of two; leaky_relu commutes with positive scaling).
// fp16 hi/lo split -> ~2^-21 rel error per term (verified r2/r4..r10).
#define XSCALE   64.0f
#define WSCALE   256.0f
#define UNSCALE  (1.0f / 16384.0f)

// LDS map (floats), per 512-thr block (16-px tile):
//  main loop: [0,7344) tar buf0 [seg*34+c] ; [7344,14688) tar buf1 ;
//             [14688,16800) refT[px*132+c]
//  epilogue (reuses dead staging regions after the last kc barrier):
//   [0,2112)      MX[ch*4+grp][ml*4+r]  per-chunk cell max       (stride 66)
//   [2112,4224)   IX[...]               per-chunk cell argmax (as float)
//   [4224,16896)  SB[q][ch][grp][ml*4+r] 6 partial sums          (stride 66)
//   [16896,16912) fx ; [16912,16928) fy
#define TB0  0
#define TB1  7344
#define TSTR 34
#define REFO 14688
#define MXo  0
#define IXo  2112
#define SBo  4224
#define FX_  16896
#define FY_  16912
#define LDSZ 16928

static __device__ __forceinline__ f16x8 cat4(f16x2 a, f16x2 b, f16x2 c, f16x2 d) {
    f16x4 ab = __builtin_shufflevector(a, b, 0, 1, 2, 3);
    f16x4 cd = __builtin_shufflevector(c, d, 0, 1, 2, 3);
    return __builtin_shufflevector(ab, cd, 0, 1, 2, 3, 4, 5, 6, 7);
}

// exact hi/lo fp16 split of a packed f32 pair
static __device__ __forceinline__ void split2(f32x2 p, f16x2& hi, f16x2& lo) {
    hi = __builtin_bit_cast(f16x2, __builtin_amdgcn_cvt_pkrtz(p.x, p.y));
    f32x2 hf; hf.x = (float)hi.x; hf.y = (float)hi.y;
    f32x2 l = p - hf;
    lo = __builtin_bit_cast(f16x2, __builtin_amdgcn_cvt_pkrtz(l.x, l.y));
}

// Fused cost-volume + flow_reg + warp v7: register-resident flow_reg epilogue.
// Block = 512 thr = 8 waves = 8 uv-chunks (11,10x7 ascending), 16-px tile.
// Grid = 512 = (b,y,xq) XCD-chunked; (512,2) -> VGPR cap 128 (2nd arg is
// min-blocks/CU on this toolchain; (512,4) spilled catastrophically in r6).
// MFMA 16x16x32_f16: A = W[16f][32c], B = X[32c][16px]; D row f=grp*4+r, col=ml
// (mapping verified r2..r10). KEY: lane (grp,ml) holds cell (f=grp*4+r, px=ml)
// for its wave's 11 uv in REGISTERS -> uv-reduction = in-register partials +
// tiny cross-chunk LDS combine (3 barriers), replacing the 4-pass/13-barrier
// pvol bounce that profiling pinned as ~40% of the kernel (bank-conflict
// counter invariant under staging rewrites).
__global__ __launch_bounds__(512, 2)
void fused_kernel(const float* __restrict__ ref,
                  const float* __restrict__ tar,
                  const float* __restrict__ pw,
                  float* __restrict__ out0,
                  float* __restrict__ warped) {
    const int t    = threadIdx.x;
    const int lane = t & 63;
    const int wid  = t >> 6;            // wave = uv-chunk
    const int ml   = lane & 15;         // B col = pixel ; A row = f
    const int grp  = lane >> 4;         // k-group (c = grp*8+j) ; D: f = grp*4+r

    // XCD-chunked bijective decode: grid 512 = 8 XCD x 64 contiguous (b,y,xq)
    const int n0 = blockIdx.x;
    const int L  = (n0 & 7) * 64 + (n0 >> 3);
    const int b  = L >> 8;
    const int y  = (L >> 2) & 63;
    const int xq = L & 3;
    const int x0 = xq * 16;

    const int start = wid ? (1 + wid * 10) : 0;   // chunk [start,start+n), n=wid?10:11

    __shared__ float lds[LDSZ];

    const float* refB = ref + ((size_t)b * C_) * HW_ + y * W_ + x0;
    const float* tarB = tar + ((size_t)b * C_) * HW_;

    // per-uv LDS seg offsets (lane-uniform)
    int off[11];
    #pragma unroll
    for (int i = 0; i < 11; ++i) {
        int uv = start + i;
        int uu = uv / 9;
        off[i] = ((uv - uu * 9) * 24 + uu) * TSTR;
    }
    const int mlg = ml * TSTR + grp * 8;

    // ---- staging role: t<288 -> (c = t&31, r = t>>5), 24-col window ----
    const int sc = t & 31;
    const int sr = t >> 5;
    const bool sact = (t < 288);
    const int ysr  = y + sr - 4;
    const bool sok = sact && ((unsigned)ysr < 64u);
    const int xlo = (xq == 0) ? 0 : (xq == 3 ? 40 : x0 - 4);
    const int sh  = x0 - 4 - xlo;                 // -4, 0, +4
    const float* tS = tarB + (size_t)sc * HW_ + (sok ? ysr : 0) * W_ + xlo;
    unsigned cmask = 0;
    #pragma unroll
    for (int j = 0; j < 24; ++j)
        if ((unsigned)(x0 - 4 + j) < 64u) cmask |= (1u << j);

    f32x4 g[6];
#define ISSUE(KC) if (sok) {                                                  \
        const float* gp = tS + (size_t)((KC) * 32) * HW_;                     \
        _Pragma("unroll")                                                     \
        for (int q = 0; q < 6; ++q) g[q] = *(const f32x4*)(gp + 4 * q);       \
    }

#define SWR(BUF, S) {                                                         \
        float* dst = lds + (BUF) + (sr * 24) * TSTR + sc;                     \
        _Pragma("unroll")                                                     \
        for (int j = 0; j < 24; ++j) {                                        \
            float v_ = 0.f;                                                   \
            if ((j + (S)) >= 0 && (j + (S)) < 24)                             \
                if ((cmask >> j) & 1u) v_ = g[(j + (S)) >> 2][(j + (S)) & 3]; \
            dst[j * TSTR] = v_;                                               \
        } }

#define SWRITE(KC, BUF) {                                                     \
        if (sok) {                                                            \
            if (sh == 0)     { SWR(BUF, 0) }                                  \
            else if (sh < 0) { SWR(BUF, -4) }                                 \
            else             { SWR(BUF, 4) }                                  \
        } else if (sact && (KC) < 2) {                                        \
            float* dst = lds + (BUF) + (sr * 24) * TSTR + sc;                 \
            _Pragma("unroll")                                                 \
            for (int j = 0; j < 24; ++j) dst[j * TSTR] = 0.f;                 \
        } }

#define TCOMP(SL, I) {                                                        \
        f16x2 xh4[4], xl4[4];                                                 \
        _Pragma("unroll")                                                     \
        for (int jp = 0; jp < 4; ++jp) {                                      \
            f32x2 p  = rv2[jp] * tv[SL][jp];                                  \
            f32x2 p1 = p * 0.1f;                                              \
            p = __builtin_elementwise_max(p, p1);                             \
            split2(p, xh4[jp], xl4[jp]);                                      \
        }                                                                     \
        f16x8 xhi = cat4(xh4[0], xh4[1], xh4[2], xh4[3]);                     \
        f16x8 xlo = cat4(xl4[0], xl4[1], xl4[2], xl4[3]);                     \
        acc[I] = __builtin_amdgcn_mfma_f32_16x16x32_f16(whi, xhi, acc[I], 0, 0, 0); \
        acc[I] = __builtin_amdgcn_mfma_f32_16x16x32_f16(wlo, xhi, acc[I], 0, 0, 0); \
        acc[I] = __builtin_amdgcn_mfma_f32_16x16x32_f16(whi, xlo, acc[I], 0, 0, 0); }

    f32x4 acc[11];
    #pragma unroll
    for (int i = 0; i < 11; ++i) acc[i] = f32x4{0.f, 0.f, 0.f, 0.f};

    // ---- prologue: stage ref + kc0, issue kc1 ----
    ISSUE(0);
    #pragma unroll
    for (int it = 0; it < 4; ++it) {
        int idx = it * 512 + t;
        int c = idx >> 4, px = idx & 15;
        lds[REFO + px * 132 + c] = refB[(size_t)c * HW_ + px] * XSCALE;
    }
    SWRITE(0, TB0);
    ISSUE(1);
    __syncthreads();

    #pragma unroll
    for (int kc = 0; kc < 4; ++kc) {
        const int tb = (kc & 1) ? TB1 : TB0;

        f32x4 wa = *(const f32x4*)(pw + ml * C_ + kc * 32 + grp * 8);
        f32x4 wb = *(const f32x4*)(pw + ml * C_ + kc * 32 + grp * 8 + 4);
        f16x2 wh[4], wl[4];
        {
            f32x2 p;
            p.x = wa.x * WSCALE; p.y = wa.y * WSCALE; split2(p, wh[0], wl[0]);
            p.x = wa.z * WSCALE; p.y = wa.w * WSCALE; split2(p, wh[1], wl[1]);
            p.x = wb.x * WSCALE; p.y = wb.y * WSCALE; split2(p, wh[2], wl[2]);
            p.x = wb.z * WSCALE; p.y = wb.w * WSCALE; split2(p, wh[3], wl[3]);
        }
        f16x8 whi = cat4(wh[0], wh[1], wh[2], wh[3]);
        f16x8 wlo = cat4(wl[0], wl[1], wl[2], wl[3]);

        f32x4 rva = *(const f32x4*)(lds + REFO + ml * 132 + kc * 32 + grp * 8);
        f32x4 rvb = *(const f32x4*)(lds + REFO + ml * 132 + kc * 32 + grp * 8 + 4);
        f32x2 rv2[4];
        rv2[0].x = rva.x; rv2[0].y = rva.y;
        rv2[1].x = rva.z; rv2[1].y = rva.w;
        rv2[2].x = rvb.x; rv2[2].y = rvb.y;
        rv2[3].x = rvb.z; rv2[3].y = rvb.w;

        f32x2 tv[2][4];
        {
            const float* tp = lds + tb + off[0] + mlg;
            tv[0][0] = *(const f32x2*)(tp);     tv[0][1] = *(const f32x2*)(tp + 2);
            tv[0][2] = *(const f32x2*)(tp + 4); tv[0][3] = *(const f32x2*)(tp + 6);
        }
        #pragma unroll
        for (int i = 0; i < 10; ++i) {
            const int nx = (i + 1) & 1, cu = i & 1;
            const float* tp = lds + tb + off[i + 1] + mlg;
            tv[nx][0] = *(const f32x2*)(tp);     tv[nx][1] = *(const f32x2*)(tp + 2);
            tv[nx][2] = *(const f32x2*)(tp + 4); tv[nx][3] = *(const f32x2*)(tp + 6);
            TCOMP(cu, i);
        }
        if (wid == 0) TCOMP(0, 10);

        if (kc == 0) { SWRITE(1, TB1); ISSUE(2); }
        else if (kc == 1) { SWRITE(2, TB0); ISSUE(3); }
        else if (kc == 2) { SWRITE(3, TB1); }
        __syncthreads();
    }

    // ================= register-resident flow_reg epilogue =================
    // unscale (exact pow2; preserves order and ties bit-exactly)
    #pragma unroll
    for (int i = 0; i < 11; ++i) acc[i] = acc[i] * UNSCALE;

    int uA[11], vA[11];
    #pragma unroll
    for (int i = 0; i < 11; ++i) {
        int uv = start + i;
        int uu = uv / 9;
        uA[i] = uu; vA[i] = uv - uu * 9;
    }

    // ---- Phase A: per-chunk cell max/argmax in registers (ascending, >) ----
    f32x4 mx = acc[0];
    f32x4 bix = f32x4{(float)start, (float)start, (float)start, (float)start};
    #pragma unroll
    for (int i = 1; i < 10; ++i)
        #pragma unroll
        for (int r = 0; r < 4; ++r)
            if (acc[i][r] > mx[r]) { mx[r] = acc[i][r]; bix[r] = (float)(start + i); }
    if (wid == 0) {
        #pragma unroll
        for (int r = 0; r < 4; ++r)
            if (acc[10][r] > mx[r]) { mx[r] = acc[10][r]; bix[r] = 10.f; }
    }
    *(f32x4*)(lds + MXo + (wid * 4 + grp) * 66 + ml * 4) = mx;
    *(f32x4*)(lds + IXo + (wid * 4 + grp) * 66 + ml * 4) = bix;
    __syncthreads();

    // ---- Phase B: global max/argmax per cell, then in-register partials ----
    f32x4 gm = *(const f32x4*)(lds + MXo + grp * 66 + ml * 4);
    f32x4 gb = *(const f32x4*)(lds + IXo + grp * 66 + ml * 4);
    #pragma unroll
    for (int ch = 1; ch < 8; ++ch) {
        f32x4 cm = *(const f32x4*)(lds + MXo + (ch * 4 + grp) * 66 + ml * 4);
        f32x4 cb = *(const f32x4*)(lds + IXo + (ch * 4 + grp) * 66 + ml * 4);
        #pragma unroll
        for (int r = 0; r < 4; ++r)
            if (cm[r] > gm[r]) { gm[r] = cm[r]; gb[r] = cb[r]; }
    }
    int ub[4], vb[4];
    #pragma unroll
    for (int r = 0; r < 4; ++r) {
        int bI = (int)gb[r];
        ub[r] = bI / 9; vb[r] = bI - 9 * ub[r];
    }

    float S[4]  = {0.f,0.f,0.f,0.f}, Aa[4] = {0.f,0.f,0.f,0.f};
    float Sx[4] = {0.f,0.f,0.f,0.f}, Sy[4] = {0.f,0.f,0.f,0.f};
    float gS[4] = {0.f,0.f,0.f,0.f}, gA[4] = {0.f,0.f,0.f,0.f};
#define PHB(i) {                                                              \
        _Pragma("unroll")                                                     \
        for (int r = 0; r < 4; ++r) {                                         \
            float d = acc[i][r] - gm[r];                                      \
            float z = __expf(d);                                              \
            gS[r] += z; gA[r] = fmaf(z, d, gA[r]);                            \
            int duc = uA[i] - ub[r], dvc = vA[i] - vb[r];                     \
            bool msk = (duc <= 3) && (duc >= -3) && (dvc <= 3) && (dvc >= -3);\
            float zm = msk ? z : 0.f, dm = msk ? d : 0.f;                     \
            S[r] += zm; Aa[r] = fmaf(zm, dm, Aa[r]);                          \
            Sx[r] = fmaf(zm, (float)(uA[i] - MD_), Sx[r]);                    \
            Sy[r] = fmaf(zm, (float)(vA[i] - MD_), Sy[r]);                    \
        } }
    #pragma unroll
    for (int i = 0; i < 10; ++i) PHB(i);
    if (wid == 0) PHB(10);

#define SST(q, a0, a1, a2, a3)                                                \
    *(f32x4*)(lds + SBo + (((q) * 8 + wid) * 4 + grp) * 66 + ml * 4) =        \
        f32x4{a0, a1, a2, a3};
    SST(0, S[0],  S[1],  S[2],  S[3])
    SST(1, Aa[0], Aa[1], Aa[2], Aa[3])
    SST(2, Sx[0], Sx[1], Sx[2], Sx[3])
    SST(3, Sy[0], Sy[1], Sy[2], Sy[3])
    SST(4, gS[0], gS[1], gS[2], gS[3])
    SST(5, gA[0], gA[1], gA[2], gA[3])
    __syncthreads();

    // ---- Phase C: wave 0 combines the 8 chunk-partials and writes out ----
    if (wid == 0) {
        f32x4 rqv[6];
        #pragma unroll
        for (int q = 0; q < 6; ++q) {
            f32x4 s = *(const f32x4*)(lds + SBo + ((q * 8) * 4 + grp) * 66 + ml * 4);
            #pragma unroll
            for (int ch = 1; ch < 8; ++ch)
                s += *(const f32x4*)(lds + SBo + ((q * 8 + ch) * 4 + grp) * 66 + ml * 4);
            rqv[q] = s;
        }
        #pragma unroll
        for (int r = 0; r < 4; ++r) {
            float invS = 1.f / rqv[0][r];
            float outx = rqv[2][r] * invS;
            float outy = rqv[3][r] * invS;
            float lent = (logf(rqv[0][r]) - rqv[1][r] * invS) * (1.0f / logf(49.0f));
            float gent = (logf(rqv[4][r]) - rqv[5][r] / rqv[4][r]) * (1.0f / logf(81.0f));
            float* op = out0 + ((size_t)(b * F_ + grp * 4 + r) * 4) * HW_
                      + y * W_ + x0 + ml;
            op[0 * HW_] = outx;
            op[1 * HW_] = outy;
            op[2 * HW_] = lent;
            op[3 * HW_] = gent;
            if (r == 0 && grp == 0) { lds[FX_ + ml] = outx; lds[FY_ + ml] = outy; }
        }
    }
    __syncthreads();

    // ---- fused warp tail: this block's 16 px, all 128 c (flow = f0) ----
    {
        const int pxi = t & 15;
        const int xw  = x0 + pxi;
        float fx = lds[FX_ + pxi], fy = lds[FY_ + pxi];
        float pxw = (float)xw + fx;
        float pyw = (float)y  + fy;
        bool inb = (fabsf(2.0f * pxw / 63.0f - 1.0f) < 1.0f) &&
                   (fabsf(2.0f * pyw / 63.0f - 1.0f) < 1.0f);
        float xf = floorf(pxw), yf = floorf(pyw);
        float wx = pxw - xf, wy = pyw - yf;
        int x0i = (int)xf, y0i = (int)yf;
        auto offn = [&](int yi, int xi, float wgt, float& mw) -> int {
            bool v = ((unsigned)xi < (unsigned)W_) && ((unsigned)yi < (unsigned)H_);
            int xc = xi < 0 ? 0 : (xi > W_ - 1 ? W_ - 1 : xi);
            int yc = yi < 0 ? 0 : (yi > H_ - 1 ? H_ - 1 : yi);
            mw = v ? wgt : 0.f;
            return yc * W_ + xc;
        };
        float m00, m01, m10, m11;
        int o00 = offn(y0i,     x0i,     (1.f - wx) * (1.f - wy), m00);
        int o01 = offn(y0i,     x0i + 1, wx * (1.f - wy),         m01);
        int o10 = offn(y0i + 1, x0i,     (1.f - wx) * wy,         m10);
        int o11 = offn(y0i + 1, x0i + 1, wx * wy,                 m11);
        #pragma unroll
        for (int it = 0; it < 4; ++it) {
            int c = (t >> 4) + 32 * it;
            const float* img = tarB + (size_t)c * HW_;
            float a = img[o00] * m00 + img[o01] * m01
                    + img[o10] * m10 + img[o11] * m11;
            warped[((size_t)(b * C_ + c)) * HW_ + y * W_ + xw] = inb ? a : 0.f;
        }
    }
}

extern "C" void kernel_launch(void* const* d_in, const int* in_sizes, int n_in,
                              void* d_out, int out_size, void* d_ws, size_t ws_size,
                              hipStream_t stream) {
    const float* ref = (const float*)d_in[0];
    const float* tar = (const float*)d_in[1];
    const float* pw  = (const float*)d_in[2];
    float* out0 = (float*)d_out;                       // (B*F, 4, H, W)
    float* out1 = out0 + (size_t)BF_ * 4 * HW_;        // (B, C, H, W)
    (void)d_ws; (void)ws_size;                         // workspace unused

    fused_kernel<<<512, 512, 0, stream>>>(ref, tar, pw, out0, out1);
}